// Round 1
// baseline (212.384 us; speedup 1.0000x reference)
//
#include <hip/hip_runtime.h>
#include <hip/hip_bf16.h>
#include <stdint.h>
#include <stddef.h>

#define B_ 8
#define S_ 2048
#define D_ 256

typedef __attribute__((ext_vector_type(8))) short short8;
typedef __attribute__((ext_vector_type(4))) float f32x4;

// round-to-nearest-even fp32 -> bf16 bit pattern
__device__ __forceinline__ short bf16of(float f) {
  union { float f; unsigned u; } x; x.f = f;
  unsigned r = x.u + 0x7FFFu + ((x.u >> 16) & 1u);
  return (short)(r >> 16);
}

// async global->LDS, 16B per lane (wave-uniform base + lane*16 layout)
__device__ __forceinline__ void async_ld16(const void* g, void* s) {
  __builtin_amdgcn_global_load_lds(
      (const __attribute__((address_space(1))) void*)g,
      (__attribute__((address_space(3))) void*)s, 16, 0, 0);
}

// ---------------- K0: UT[n][k] = bf16(U[k][n]) ----------------
__global__ void k_prep_u(const float* __restrict__ U, short* __restrict__ UT) {
  int n = blockIdx.x;
  int k = threadIdx.x;
  UT[n * D_ + k] = bf16of(U[k * D_ + n]);
}

// ---------------- K1: Ahat = head_flat @ U (bf16 out), hs = head @ wh ----------------
__launch_bounds__(256, 2)
__global__ void k_ahat(const float* __restrict__ head,
                       const short* __restrict__ UT,
                       const float* __restrict__ W,   // wh = W[0..255]
                       short* __restrict__ Ahat,
                       float* __restrict__ hs) {
  __shared__ __align__(16) short sA[128 * 32];
  __shared__ __align__(16) short sB[128 * 32];
  const int t = threadIdx.x;
  const int w = t >> 6;
  const int l = t & 63;
  const int ntile = blockIdx.x;        // 0..1
  const int mbase = blockIdx.y * 128;  // 0..16256
  const int nbase = ntile * 128;

  f32x4 acc[4][4];
#pragma unroll
  for (int i = 0; i < 4; ++i)
#pragma unroll
    for (int j = 0; j < 4; ++j) acc[i][j] = (f32x4)0.0f;

  float hsacc0 = 0.f, hsacc1 = 0.f;
  const int row0 = t >> 2;   // 0..63
  const int cc   = t & 3;    // which 8-float chunk of the 32-wide K tile

  for (int kb = 0; kb < 8; ++kb) {
    const int kbase = kb * 32;
    __syncthreads();
    // B tile: UT rows [nbase, nbase+128), K cols [kbase, kbase+32), bf16, async
#pragma unroll
    for (int c = 0; c < 2; ++c) {
      int q = c * 256 + t;
      int r = q >> 2, qc = q & 3;
      async_ld16(UT + (nbase + r) * D_ + kbase + qc * 8, (char*)sB + q * 16);
    }
    // A tile: head fp32 -> bf16 through registers; fuse hs partial
#pragma unroll
    for (int c = 0; c < 2; ++c) {
      int r = 64 * c + row0;
      const float4* gp = (const float4*)(head + (size_t)(mbase + r) * D_ + kbase + cc * 8);
      float4 v0 = gp[0], v1 = gp[1];
      const float4* wp = (const float4*)(W + kbase + cc * 8);
      float4 w0 = wp[0], w1 = wp[1];
      float p = v0.x * w0.x + v0.y * w0.y + v0.z * w0.z + v0.w * w0.w
              + v1.x * w1.x + v1.y * w1.y + v1.z * w1.z + v1.w * w1.w;
      if (c == 0) hsacc0 += p; else hsacc1 += p;
      short8 pk;
      pk[0] = bf16of(v0.x); pk[1] = bf16of(v0.y); pk[2] = bf16of(v0.z); pk[3] = bf16of(v0.w);
      pk[4] = bf16of(v1.x); pk[5] = bf16of(v1.y); pk[6] = bf16of(v1.z); pk[7] = bf16of(v1.w);
      *(short8*)(&sA[(64 * c + row0) * 32 + cc * 8]) = pk;
    }
    __syncthreads();

    const short8* pA = (const short8*)sA;
    const short8* pB = (const short8*)sB;
    const int arow = ((w >> 1) * 64) + (l & 15);
    const int brow = ((w & 1) * 64) + (l & 15);
    const int quad = l >> 4;
    short8 aF[4], bF[4];
#pragma unroll
    for (int mt = 0; mt < 4; ++mt) aF[mt] = pA[(arow + mt * 16) * 4 + quad];
#pragma unroll
    for (int nt = 0; nt < 4; ++nt) bF[nt] = pB[(brow + nt * 16) * 4 + quad];
#pragma unroll
    for (int mt = 0; mt < 4; ++mt)
#pragma unroll
      for (int nt = 0; nt < 4; ++nt)
        acc[mt][nt] = __builtin_amdgcn_mfma_f32_16x16x32_bf16(aF[mt], bF[nt], acc[mt][nt], 0, 0, 0);
  }

  // hs: combine 4 adjacent lanes (k-chunk partials) -> full row sums
  {
    float v = hsacc0;
    v += __shfl_xor(v, 1);
    v += __shfl_xor(v, 2);
    if (cc == 0 && ntile == 0) hs[mbase + row0] = v;
    float u = hsacc1;
    u += __shfl_xor(u, 1);
    u += __shfl_xor(u, 2);
    if (cc == 0 && ntile == 0) hs[mbase + 64 + row0] = u;
  }

  // store Ahat (bf16)
  const int quad = l >> 4;
#pragma unroll
  for (int mt = 0; mt < 4; ++mt) {
#pragma unroll
    for (int r = 0; r < 4; ++r) {
      int grow = mbase + (w >> 1) * 64 + mt * 16 + quad * 4 + r;
#pragma unroll
      for (int nt = 0; nt < 4; ++nt) {
        int gcol = nbase + (w & 1) * 64 + nt * 16 + (l & 15);
        Ahat[(size_t)grow * D_ + gcol] = bf16of(acc[mt][nt][r]);
      }
    }
  }
}

// ---------------- K2: out[b] = Ahat[b] @ dep[b]^T + hs[i] + ds[o] + bias ----------------
__launch_bounds__(256, 2)
__global__ void k_main(const short* __restrict__ Ahat,
                       const float* __restrict__ dep,
                       const float* __restrict__ W,   // wd = W + 256
                       const float* __restrict__ hs,
                       const float* __restrict__ eb,
                       float* __restrict__ out) {
  __shared__ __align__(16) short sA[128 * 32];
  __shared__ __align__(16) short sB[128 * 32];
  __shared__ float hs_s[128];
  __shared__ float ds_s[128];
  const int t = threadIdx.x;
  const int w = t >> 6;
  const int l = t & 63;
  const int b = blockIdx.z;
  const int mbase = blockIdx.y * 128;  // i rows
  const int nbase = blockIdx.x * 128;  // o rows (dep)
  const float* wd = W + D_;

  if (t < 128) hs_s[t] = hs[b * S_ + mbase + t];

  f32x4 acc[4][4];
#pragma unroll
  for (int i = 0; i < 4; ++i)
#pragma unroll
    for (int j = 0; j < 4; ++j) acc[i][j] = (f32x4)0.0f;

  float dsacc0 = 0.f, dsacc1 = 0.f;
  const int row0 = t >> 2;
  const int cc   = t & 3;

  for (int kb = 0; kb < 8; ++kb) {
    const int kbase = kb * 32;
    __syncthreads();
    // A tile: Ahat bf16, async direct-to-LDS
#pragma unroll
    for (int c = 0; c < 2; ++c) {
      int q = c * 256 + t;
      int r = q >> 2, qc = q & 3;
      async_ld16(Ahat + (size_t)(b * S_ + mbase + r) * D_ + kbase + qc * 8, (char*)sA + q * 16);
    }
    // B tile: dep fp32 -> bf16 via regs; fuse ds partial
#pragma unroll
    for (int c = 0; c < 2; ++c) {
      int r = 64 * c + row0;
      const float4* gp = (const float4*)(dep + (size_t)(b * S_ + nbase + r) * D_ + kbase + cc * 8);
      float4 v0 = gp[0], v1 = gp[1];
      const float4* wp = (const float4*)(wd + kbase + cc * 8);
      float4 w0 = wp[0], w1 = wp[1];
      float p = v0.x * w0.x + v0.y * w0.y + v0.z * w0.z + v0.w * w0.w
              + v1.x * w1.x + v1.y * w1.y + v1.z * w1.z + v1.w * w1.w;
      if (c == 0) dsacc0 += p; else dsacc1 += p;
      short8 pk;
      pk[0] = bf16of(v0.x); pk[1] = bf16of(v0.y); pk[2] = bf16of(v0.z); pk[3] = bf16of(v0.w);
      pk[4] = bf16of(v1.x); pk[5] = bf16of(v1.y); pk[6] = bf16of(v1.z); pk[7] = bf16of(v1.w);
      *(short8*)(&sB[(64 * c + row0) * 32 + cc * 8]) = pk;
    }
    __syncthreads();

    const short8* pA = (const short8*)sA;
    const short8* pB = (const short8*)sB;
    const int arow = ((w >> 1) * 64) + (l & 15);
    const int brow = ((w & 1) * 64) + (l & 15);
    const int quad = l >> 4;
    short8 aF[4], bF[4];
#pragma unroll
    for (int mt = 0; mt < 4; ++mt) aF[mt] = pA[(arow + mt * 16) * 4 + quad];
#pragma unroll
    for (int nt = 0; nt < 4; ++nt) bF[nt] = pB[(brow + nt * 16) * 4 + quad];
#pragma unroll
    for (int mt = 0; mt < 4; ++mt)
#pragma unroll
      for (int nt = 0; nt < 4; ++nt)
        acc[mt][nt] = __builtin_amdgcn_mfma_f32_16x16x32_bf16(aF[mt], bF[nt], acc[mt][nt], 0, 0, 0);
  }

  // ds: combine k-chunk partials across 4 adjacent lanes, publish to LDS
  {
    float v = dsacc0;
    v += __shfl_xor(v, 1);
    v += __shfl_xor(v, 2);
    if (cc == 0) ds_s[row0] = v;
    float u = dsacc1;
    u += __shfl_xor(u, 1);
    u += __shfl_xor(u, 2);
    if (cc == 0) ds_s[64 + row0] = u;
  }
  __syncthreads();

  const float bias = eb[0];
  const int quad = l >> 4;
#pragma unroll
  for (int mt = 0; mt < 4; ++mt) {
#pragma unroll
    for (int r = 0; r < 4; ++r) {
      int lrow = (w >> 1) * 64 + mt * 16 + quad * 4 + r;
      float hv = hs_s[lrow] + bias;
      int grow = b * S_ + mbase + lrow;
      float* orow = out + (size_t)grow * S_ + nbase;
#pragma unroll
      for (int nt = 0; nt < 4; ++nt) {
        int lcol = (w & 1) * 64 + nt * 16 + (l & 15);
        orow[lcol] = acc[mt][nt][r] + hv + ds_s[lcol];
      }
    }
  }
}

extern "C" void kernel_launch(void* const* d_in, const int* in_sizes, int n_in,
                              void* d_out, int out_size, void* d_ws, size_t ws_size,
                              hipStream_t stream) {
  const float* head = (const float*)d_in[0];
  const float* dep  = (const float*)d_in[1];
  const float* U    = (const float*)d_in[2];
  const float* W    = (const float*)d_in[3];  // (1, 512): wh | wd
  const float* eb   = (const float*)d_in[4];
  float* out = (float*)d_out;

  char* ws = (char*)d_ws;
  short* UT   = (short*)ws;                    // 256*256*2   = 128 KB
  float* hs   = (float*)(ws + (128 << 10));    // 16384*4     = 64 KB
  short* Ahat = (short*)(ws + (192 << 10));    // 16384*256*2 = 8 MB

  k_prep_u<<<dim3(256), dim3(256), 0, stream>>>(U, UT);
  k_ahat<<<dim3(2, 128), dim3(256), 0, stream>>>(head, UT, W, Ahat, hs);
  k_main<<<dim3(16, 16, 8), dim3(256), 0, stream>>>(Ahat, dep, W, hs, eb, out);
}

// Round 2
// 191.183 us; speedup vs baseline: 1.1109x; 1.1109x over previous
//
#include <hip/hip_runtime.h>
#include <hip/hip_bf16.h>
#include <stdint.h>
#include <stddef.h>

#define B_ 8
#define S_ 2048
#define D_ 256
#define NROWS (B_ * S_)  // 16384

typedef __attribute__((ext_vector_type(8))) short short8;
typedef __attribute__((ext_vector_type(4))) short short4v;
typedef __attribute__((ext_vector_type(4))) float f32x4;

// round-to-nearest-even fp32 -> bf16 bit pattern
__device__ __forceinline__ short bf16of(float f) {
  union { float f; unsigned u; } x; x.f = f;
  unsigned r = x.u + 0x7FFFu + ((x.u >> 16) & 1u);
  return (short)(r >> 16);
}

// async global->LDS, 16B per lane (wave-uniform base + lane*16 layout)
__device__ __forceinline__ void async_ld16(const void* g, void* s) {
  __builtin_amdgcn_global_load_lds(
      (const __attribute__((address_space(1))) void*)g,
      (__attribute__((address_space(3))) void*)s, 16, 0, 0);
}

// ---------------- K0: UT[n][k] = bf16(U[k][n]) ----------------
__global__ void k_prep_u(const float* __restrict__ U, short* __restrict__ UT) {
  int n = blockIdx.x;
  int k = threadIdx.x;
  UT[n * D_ + k] = bf16of(U[k * D_ + n]);
}

// ---- K_rows: hs = head@wh, ds = dep@wd (fp32 exact); headB/depB = bf16(X) ----
// grid (4096, 2), block 256 (4 waves, 1 row per wave)
__global__ void k_rows(const float* __restrict__ head, const float* __restrict__ dep,
                       const float* __restrict__ W,
                       float* __restrict__ hs, float* __restrict__ ds,
                       short* __restrict__ headB, short* __restrict__ depB) {
  const float* X; const float* wv; float* sv; short* XB;
  if (blockIdx.y == 0) { X = head; wv = W;      sv = hs; XB = headB; }
  else                 { X = dep;  wv = W + D_; sv = ds; XB = depB;  }
  const int row = blockIdx.x * 4 + (threadIdx.x >> 6);
  const int l = threadIdx.x & 63;
  const float4 v  = *(const float4*)(X + (size_t)row * D_ + l * 4);
  const float4 wq = *(const float4*)(wv + l * 4);
  short4v pk;
  pk[0] = bf16of(v.x); pk[1] = bf16of(v.y); pk[2] = bf16of(v.z); pk[3] = bf16of(v.w);
  *(short4v*)(XB + (size_t)row * D_ + l * 4) = pk;
  float p = v.x * wq.x + v.y * wq.y + v.z * wq.z + v.w * wq.w;
  p += __shfl_xor(p, 1); p += __shfl_xor(p, 2); p += __shfl_xor(p, 4);
  p += __shfl_xor(p, 8); p += __shfl_xor(p, 16); p += __shfl_xor(p, 32);
  if (l == 0) sv[row] = p;
}

// ---------------- K1: Ahat = headB @ U (bf16), all-async staging ----------------
// grid (2, 128): x = U-col tile (nbase), y = flat row tile (mbase)
__launch_bounds__(256, 2)
__global__ void k_ahat(const short* __restrict__ headB, const short* __restrict__ UT,
                       short* __restrict__ Ahat) {
  __shared__ __align__(16) short sU[4 * 128 * 32];  // 32 KB: U-cols (A-operand, m = n_col)
  __shared__ __align__(16) short sH[4 * 128 * 32];  // 32 KB: head rows (B-operand, n = i)
  const int t = threadIdx.x;
  const int w = t >> 6;
  const int l = t & 63;
  const int quad = l >> 4;
  const int nbase = blockIdx.x * 128;
  const int mbase = blockIdx.y * 128;

  f32x4 acc[4][4];
#pragma unroll
  for (int i = 0; i < 4; ++i)
#pragma unroll
    for (int j = 0; j < 4; ++j) acc[i][j] = (f32x4)0.0f;

  for (int it = 0; it < 2; ++it) {  // BK = 128
    __syncthreads();
#pragma unroll
    for (int kb = 0; kb < 4; ++kb) {
#pragma unroll
      for (int c = 0; c < 2; ++c) {
        int q = c * 256 + t;
        int r = q >> 2, qc = q & 3;
        int kk = it * 128 + kb * 32 + qc * 8;
        async_ld16(UT + (size_t)(nbase + r) * D_ + kk, (char*)sU + kb * 8192 + q * 16);
        async_ld16(headB + (size_t)(mbase + r) * D_ + kk, (char*)sH + kb * 8192 + q * 16);
      }
    }
    __syncthreads();
    const short8* pU = (const short8*)sU;
    const short8* pH = (const short8*)sH;
#pragma unroll
    for (int kb = 0; kb < 4; ++kb) {
      short8 aF[4], bF[4];
#pragma unroll
      for (int mt = 0; mt < 4; ++mt)
        aF[mt] = pU[(kb * 128 + (w >> 1) * 64 + mt * 16 + (l & 15)) * 4 + quad];
#pragma unroll
      for (int nt = 0; nt < 4; ++nt)
        bF[nt] = pH[(kb * 128 + (w & 1) * 64 + nt * 16 + (l & 15)) * 4 + quad];
#pragma unroll
      for (int mt = 0; mt < 4; ++mt)
#pragma unroll
        for (int nt = 0; nt < 4; ++nt)
          acc[mt][nt] = __builtin_amdgcn_mfma_f32_16x16x32_bf16(aF[mt], bF[nt], acc[mt][nt], 0, 0, 0);
    }
  }

  // D[m=n_col][n=i] -> lane holds 4 consecutive n_col for fixed i: short4 stores
#pragma unroll
  for (int mt = 0; mt < 4; ++mt) {
    int n_loc = (w >> 1) * 64 + mt * 16 + quad * 4;
#pragma unroll
    for (int nt = 0; nt < 4; ++nt) {
      int i_loc = (w & 1) * 64 + nt * 16 + (l & 15);
      short4v pk;
      pk[0] = bf16of(acc[mt][nt][0]); pk[1] = bf16of(acc[mt][nt][1]);
      pk[2] = bf16of(acc[mt][nt][2]); pk[3] = bf16of(acc[mt][nt][3]);
      *(short4v*)(Ahat + (size_t)(mbase + i_loc) * D_ + nbase + n_loc) = pk;
    }
  }
}

// ------- K2: out[b,i,o] = sum_k Ahat[b,i,k] depB[b,o,k] + hs[i] + ds[o] + bias -------
// grid (16 o-tiles, 16 i-tiles, 8 b); A-operand = depB (m = o), B-operand = Ahat (n = i)
__launch_bounds__(256, 3)
__global__ void k_main(const short* __restrict__ Ahat, const short* __restrict__ depB,
                       const float* __restrict__ hs, const float* __restrict__ ds,
                       const float* __restrict__ eb, float* __restrict__ out) {
  __shared__ __align__(16) short sA[2 * 128 * 32];  // 16 KB: Ahat rows (i), BK=64 slice
  __shared__ __align__(16) short sD[2 * 128 * 32];  // 16 KB: dep rows (o), BK=64 slice
  __shared__ float hs_s[128];
  __shared__ float ds_s[128];
  const int t = threadIdx.x;
  const int w = t >> 6;
  const int l = t & 63;
  const int quad = l >> 4;
  const int b = blockIdx.z;
  const int mbase = blockIdx.y * 128;  // i
  const int nbase = blockIdx.x * 128;  // o

  if (t < 128) hs_s[t] = hs[b * S_ + mbase + t];
  else         ds_s[t - 128] = ds[b * S_ + nbase + t - 128];

  f32x4 acc[4][4];
#pragma unroll
  for (int i = 0; i < 4; ++i)
#pragma unroll
    for (int j = 0; j < 4; ++j) acc[i][j] = (f32x4)0.0f;

  for (int it = 0; it < 4; ++it) {  // BK = 64
    __syncthreads();
#pragma unroll
    for (int kb = 0; kb < 2; ++kb) {
#pragma unroll
      for (int c = 0; c < 2; ++c) {
        int q = c * 256 + t;
        int r = q >> 2, qc = q & 3;
        int kk = it * 64 + kb * 32 + qc * 8;
        async_ld16(Ahat + (size_t)(b * S_ + mbase + r) * D_ + kk, (char*)sA + kb * 8192 + q * 16);
        async_ld16(depB + (size_t)(b * S_ + nbase + r) * D_ + kk, (char*)sD + kb * 8192 + q * 16);
      }
    }
    __syncthreads();
    const short8* pA = (const short8*)sA;
    const short8* pD = (const short8*)sD;
#pragma unroll
    for (int kb = 0; kb < 2; ++kb) {
      short8 aF[4], bF[4];
#pragma unroll
      for (int mt = 0; mt < 4; ++mt)  // A-operand: dep rows (o)
        aF[mt] = pD[(kb * 128 + (w >> 1) * 64 + mt * 16 + (l & 15)) * 4 + quad];
#pragma unroll
      for (int nt = 0; nt < 4; ++nt)  // B-operand: Ahat rows (i)
        bF[nt] = pA[(kb * 128 + (w & 1) * 64 + nt * 16 + (l & 15)) * 4 + quad];
#pragma unroll
      for (int mt = 0; mt < 4; ++mt)
#pragma unroll
        for (int nt = 0; nt < 4; ++nt)
          acc[mt][nt] = __builtin_amdgcn_mfma_f32_16x16x32_bf16(aF[mt], bF[nt], acc[mt][nt], 0, 0, 0);
    }
  }

  const float bias = eb[0];
#pragma unroll
  for (int mt = 0; mt < 4; ++mt) {
    int o_loc = (w >> 1) * 64 + mt * 16 + quad * 4;
    float4 dsv = *(const float4*)&ds_s[o_loc];
#pragma unroll
    for (int nt = 0; nt < 4; ++nt) {
      int i_loc = (w & 1) * 64 + nt * 16 + (l & 15);
      float hv = hs_s[i_loc] + bias;
      f32x4 a = acc[mt][nt];
      float4 o4;
      o4.x = a[0] + hv + dsv.x;
      o4.y = a[1] + hv + dsv.y;
      o4.z = a[2] + hv + dsv.z;
      o4.w = a[3] + hv + dsv.w;
      *(float4*)(out + (size_t)(b * S_ + mbase + i_loc) * S_ + nbase + o_loc) = o4;
    }
  }
}

extern "C" void kernel_launch(void* const* d_in, const int* in_sizes, int n_in,
                              void* d_out, int out_size, void* d_ws, size_t ws_size,
                              hipStream_t stream) {
  const float* head = (const float*)d_in[0];
  const float* dep  = (const float*)d_in[1];
  const float* U    = (const float*)d_in[2];
  const float* W    = (const float*)d_in[3];  // (1, 512): wh | wd
  const float* eb   = (const float*)d_in[4];
  float* out = (float*)d_out;

  char* ws = (char*)d_ws;
  short* UT    = (short*)ws;                       // 256*256*2     = 128 KB
  float* hs    = (float*)(ws + (128 << 10));       // 16384*4       = 64 KB
  float* ds    = (float*)(ws + (192 << 10));       // 16384*4       = 64 KB
  short* headB = (short*)(ws + (256 << 10));       // 16384*256*2   = 8 MB
  short* depB  = (short*)(ws + (256 << 10) + (8 << 20));
  short* Ahat  = (short*)(ws + (256 << 10) + (16 << 20));

  k_prep_u<<<dim3(256), dim3(256), 0, stream>>>(U, UT);
  k_rows<<<dim3(NROWS / 4, 2), dim3(256), 0, stream>>>(head, dep, W, hs, ds, headB, depB);
  k_ahat<<<dim3(2, 128), dim3(256), 0, stream>>>(headB, UT, Ahat);
  k_main<<<dim3(16, 16, 8), dim3(256), 0, stream>>>(Ahat, depB, hs, ds, eb, out);
}